// Round 1
// 91.738 us; speedup vs baseline: 1.0169x; 1.0169x over previous
//
#include <hip/hip_runtime.h>

#define NPTS 4096      // points per cloud
#define NB   4         // batch
#define KP   512       // keypoints
#define HUBER_C 0.01f
#define HALF_PTS (NB * NPTS)          // 16384
#define TOT_PTS  (2 * NB * NPTS)      // 32768
#define OSTRIPE 64                    // others per stripe (64 stripes)
#define QCHUNK  1024                  // queries per block (4 per thread)
#define NOC (NPTS / OSTRIPE)          // 64
#define NQC (NPTS / QCHUNK)           // 4
#define GAL_BLOCKS (2 * NB * NQC * NOC)   // 2048

typedef float v2f __attribute__((ext_vector_type(2)));

// ws layout:
//   [0,      128 KB)  unsigned minarr[TOT_PTS]
//   [128 KB, +64 B )  ctrl: [0]=float acc (nc loss)

// Tuning log (MI355X):
//   R3: QPT=2, 512 blocks  -> main 49 us (load-latency bound, 15% occ)
//   R4: QPT=4, 1024 blocks -> total 94.8
//   R5: QPT=1, 1024 blocks -> 104.4 (loads/block 4x; atomics NOT the issue)
//   R6: R4 + 8-wide load batch -> 95.4 (neutral; latency already covered?)
//   R7: R4 + packed-fp32 inner loop -> 93.3 [prev best] (pk_fma is rate-
//       neutral on f32 -> instr-count cut can't help; kernel is stall-bound)
//   R8 (this): OSTRIPE 64 -> 2048 GAL blocks (8 waves/SIMD), o-stripe staged
//       in LDS (broadcast ds_read_b128, no vmcnt in hot loop), prep_kernel
//       deleted (norms on the fly, init via tiny kernel).

// ---------------- helpers ----------------

__device__ inline void wave_reduce_add_to(float v, float* target) {
    #pragma unroll
    for (int off = 32; off; off >>= 1) v += __shfl_down(v, off, 64);
    if ((threadIdx.x & 63) == 0) atomicAdd(target, v);
}

__device__ inline float huber_f(float x) {
    return (x < HUBER_C) ? 0.5f * x * x
                         : fmaf(HUBER_C, x, -0.5f * HUBER_C * HUBER_C);
}

__device__ inline v2f splat2(float s) { v2f r; r.x = s; r.y = s; return r; }

// ---------------- kernels ----------------

// grid = TOT_PTS/4/256 = 32 blocks. minarr <- +inf, acc <- 0.
__global__ __launch_bounds__(256) void init_kernel(
    uint4* __restrict__ minarr4, unsigned* __restrict__ ctrl)
{
    int i = blockIdx.x * 256 + threadIdx.x;      // [0, 8192)
    minarr4[i] = make_uint4(0x7F800000u, 0x7F800000u, 0x7F800000u, 0x7F800000u);
    if (i == 0) ctrl[0] = 0u;                    // acc = 0.0f
}

// Fused main: blocks [0,GAL_BLOCKS) gal pairwise-min; then knn; then kp.
__global__ __launch_bounds__(256, 6) void main_kernel(
    const float* __restrict__ srcT, const float* __restrict__ tgtT,
    unsigned* __restrict__ minarr,
    const float* __restrict__ skp, const float* __restrict__ tkp,
    const float* __restrict__ R, const float* __restrict__ T,
    const float* __restrict__ aknn, const float* __restrict__ bknn,
    const int* __restrict__ kptr, float* __restrict__ acc,
    int knn_blocks, int knn_quads)
{
    __shared__ float4 olds[OSTRIPE];
    const int bid = blockIdx.x;
    const int tid = threadIdx.x;

    if (bid < GAL_BLOCKS) {
        // ---- global-align pairwise min ----
        const int oc  = bid & (NOC - 1);       // 64 other-stripes of 64
        const int b   = (bid >> 6) & 3;
        const int dir = (bid >> 8) & 1;        // 0: queries=src, 1: queries=tgt
        const int qc  = bid >> 9;              // 4 query-chunks of 1024
        const float* qb = (dir ? tgtT : srcT) + b * 3 * NPTS;
        const float* ob = (dir ? srcT : tgtT) + b * 3 * NPTS;

        // stage o-stripe (xyz + |o|^2) into LDS: one coalesced 64-lane load
        if (tid < OSTRIPE) {
            int oi = oc * OSTRIPE + tid;
            float ox = ob[oi], oy = ob[NPTS + oi], oz = ob[2 * NPTS + oi];
            olds[tid] = make_float4(ox, oy, oz,
                                    fmaf(ox, ox, fmaf(oy, oy, oz * oz)));
        }

        // 4 queries packed as 2 float2 pairs: p in {0,1}, lanes {2p, 2p+1}
        v2f ax2[2], ay2[2], az2[2], mm2[2];
        float qw[4];
        #pragma unroll
        for (int p = 0; p < 2; ++p) {
            int ia = qc * QCHUNK + (2 * p) * 256 + tid;
            int ib = ia + 256;
            float Ax = qb[ia], Ay = qb[NPTS + ia], Az = qb[2 * NPTS + ia];
            float Bx = qb[ib], By = qb[NPTS + ib], Bz = qb[2 * NPTS + ib];
            ax2[p].x = -2.0f * Ax; ax2[p].y = -2.0f * Bx;
            ay2[p].x = -2.0f * Ay; ay2[p].y = -2.0f * By;
            az2[p].x = -2.0f * Az; az2[p].y = -2.0f * Bz;
            qw[2 * p]     = fmaf(Ax, Ax, fmaf(Ay, Ay, Az * Az));
            qw[2 * p + 1] = fmaf(Bx, Bx, fmaf(By, By, Bz * Bz));
            mm2[p].x = 3.0e38f; mm2[p].y = 3.0e38f;
        }
        __syncthreads();

        // per o-pair per q-pair: 6 v_pk_fma_f32 + 2 v_min3_f32
        auto step2 = [&](const float4& u, const float4& v) {
            #pragma unroll
            for (int p = 0; p < 2; ++p) {
                v2f t0 = __builtin_elementwise_fma(splat2(u.x), ax2[p],
                         __builtin_elementwise_fma(splat2(u.y), ay2[p],
                         __builtin_elementwise_fma(splat2(u.z), az2[p], splat2(u.w))));
                v2f t1 = __builtin_elementwise_fma(splat2(v.x), ax2[p],
                         __builtin_elementwise_fma(splat2(v.y), ay2[p],
                         __builtin_elementwise_fma(splat2(v.z), az2[p], splat2(v.w))));
                mm2[p].x = fminf(mm2[p].x, fminf(t0.x, t1.x));   // v_min3_f32
                mm2[p].y = fminf(mm2[p].y, fminf(t0.y, t1.y));
            }
        };

        #pragma unroll 4
        for (int j = 0; j < OSTRIPE; j += 4) {
            float4 o0 = olds[j], o1 = olds[j + 1];
            float4 o2 = olds[j + 2], o3 = olds[j + 3];
            step2(o0, o1);
            step2(o2, o3);
        }

        unsigned* marr = minarr + (dir * NB + b) * NPTS + qc * QCHUNK + tid;
        #pragma unroll
        for (int p = 0; p < 2; ++p) {
            float d0 = fmaxf(qw[2 * p]     + mm2[p].x, 0.0f);  // >=0: atomicMin-safe
            float d1 = fmaxf(qw[2 * p + 1] + mm2[p].y, 0.0f);
            atomicMin(&marr[(2 * p) * 256],     __float_as_uint(d0));
            atomicMin(&marr[(2 * p + 1) * 256], __float_as_uint(d1));
        }
    } else if (bid < GAL_BLOCKS + knn_blocks) {
        // ---- knn consensus: sum((a-b)^2)/k ----
        int i = (bid - GAL_BLOCKS) * 256 + tid;
        float sum = 0.0f;
        if (i < knn_quads) {
            float4 va = ((const float4*)aknn)[i];
            float4 vb = ((const float4*)bknn)[i];
            float dx = va.x - vb.x, dy = va.y - vb.y;
            float dz = va.z - vb.z, dw = va.w - vb.w;
            sum = fmaf(dx, dx, fmaf(dy, dy, fmaf(dz, dz, dw * dw)));
        }
        float scale = 1.0f / (float)(*kptr);
        wave_reduce_add_to(sum * scale, acc);
    } else {
        // ---- keypoints: sum((R@s + t - g)^2) ----
        int i = (bid - GAL_BLOCKS - knn_blocks) * 256 + tid;   // [0, NB*KP)
        int b = i >> 9;
        int n = i & (KP - 1);
        const float* r = R + b * 9;
        const float* t = T + b * 3;
        const float* s = skp + b * 3 * KP;
        const float* g = tkp + b * 3 * KP;
        float sx = s[n], sy = s[KP + n], sz = s[2 * KP + n];
        float sum = 0.0f;
        #pragma unroll
        for (int d = 0; d < 3; ++d) {
            float v = fmaf(r[d*3+0], sx, fmaf(r[d*3+1], sy, fmaf(r[d*3+2], sz, t[d])))
                      - g[d * KP + n];
            sum = fmaf(v, v, sum);
        }
        wave_reduce_add_to(sum, acc);
    }
}

// single block: huber over the 32768 mins, write both outputs
__global__ __launch_bounds__(1024) void finalize_kernel(
    const unsigned* __restrict__ minarr, const float* __restrict__ acc,
    float* __restrict__ out)
{
    __shared__ float red[16];
    const int tid = threadIdx.x;
    const uint4* m4 = (const uint4*)minarr;
    float sum = 0.0f;
    #pragma unroll
    for (int r = 0; r < 8; ++r) {            // 1024 thr * 8 * uint4 = 32768
        uint4 v = m4[r * 1024 + tid];
        sum += huber_f(__uint_as_float(v.x)) + huber_f(__uint_as_float(v.y))
             + huber_f(__uint_as_float(v.z)) + huber_f(__uint_as_float(v.w));
    }
    #pragma unroll
    for (int off = 32; off; off >>= 1) sum += __shfl_down(sum, off, 64);
    if ((tid & 63) == 0) red[tid >> 6] = sum;
    __syncthreads();
    if (tid == 0) {
        float s = 0.0f;
        #pragma unroll
        for (int i = 0; i < 16; ++i) s += red[i];
        out[1] = s;                              // gal
        out[0] = *acc;                           // neighborhood consensus
    }
}

// ---------------- fallback (no workspace) ----------------

__global__ void zero_out_kernel(float* __restrict__ out) {
    if (threadIdx.x < 2) out[threadIdx.x] = 0.0f;
}

__global__ __launch_bounds__(256) void gal_direct_kernel(
    const float* __restrict__ srcT, const float* __restrict__ tgtT,
    float* __restrict__ gal_out)
{
    const int dir = blockIdx.y >> 2;
    const int b   = blockIdx.y & 3;
    const float* qb = (dir ? tgtT : srcT) + b * 3 * NPTS;
    const float* ob = (dir ? srcT : tgtT) + b * 3 * NPTS;
    const int qi = blockIdx.x * 256 + threadIdx.x;
    const float qx = qb[qi], qy = qb[NPTS + qi], qz = qb[2 * NPTS + qi];
    float m = 3.0e38f;
    #pragma unroll 4
    for (int j = 0; j < NPTS; ++j) {
        float dx = qx - ob[j], dy = qy - ob[NPTS + j], dz = qz - ob[2 * NPTS + j];
        m = fminf(m, fmaf(dx, dx, fmaf(dy, dy, dz * dz)));
    }
    wave_reduce_add_to(huber_f(m), gal_out);
}

__global__ __launch_bounds__(256) void kp_kernel(
    const float* __restrict__ skp, const float* __restrict__ tkp,
    const float* __restrict__ R, const float* __restrict__ T,
    float* __restrict__ acc)
{
    int i = blockIdx.x * 256 + threadIdx.x;
    int b = i >> 9, n = i & (KP - 1);
    const float* r = R + b * 9;
    const float* t = T + b * 3;
    const float* s = skp + b * 3 * KP;
    const float* g = tkp + b * 3 * KP;
    float sx = s[n], sy = s[KP + n], sz = s[2 * KP + n];
    float sum = 0.0f;
    #pragma unroll
    for (int d = 0; d < 3; ++d) {
        float v = fmaf(r[d*3+0], sx, fmaf(r[d*3+1], sy, fmaf(r[d*3+2], sz, t[d])))
                  - g[d * KP + n];
        sum = fmaf(v, v, sum);
    }
    wave_reduce_add_to(sum, acc);
}

__global__ __launch_bounds__(256) void knn_kernel(
    const float* __restrict__ a, const float* __restrict__ b,
    const int* __restrict__ kptr, float* __restrict__ acc, int quads)
{
    int i = blockIdx.x * 256 + threadIdx.x;
    float sum = 0.0f;
    if (i < quads) {
        float4 va = ((const float4*)a)[i];
        float4 vb = ((const float4*)b)[i];
        float dx = va.x - vb.x, dy = va.y - vb.y;
        float dz = va.z - vb.z, dw = va.w - vb.w;
        sum = fmaf(dx, dx, fmaf(dy, dy, fmaf(dz, dz, dw * dw)));
    }
    float scale = 1.0f / (float)(*kptr);
    wave_reduce_add_to(sum * scale, acc);
}

// ---------------- launch ----------------

extern "C" void kernel_launch(void* const* d_in, const int* in_sizes, int n_in,
                              void* d_out, int out_size, void* d_ws, size_t ws_size,
                              hipStream_t stream) {
    const float* skp  = (const float*)d_in[0];   // (B,3,KP)
    const float* tkp  = (const float*)d_in[1];   // (B,3,KP)
    const float* R    = (const float*)d_in[2];   // (B,3,3)
    const float* T    = (const float*)d_in[3];   // (B,3)
    const float* aknn = (const float*)d_in[4];   // (B,3,KP,K)
    const float* bknn = (const float*)d_in[5];   // (B,3,KP,K)
    const int*   kptr = (const int*)d_in[6];     // scalar k
    const float* srcT = (const float*)d_in[7];   // (B,3,N)
    const float* tgtT = (const float*)d_in[8];   // (B,3,N)
    float* out = (float*)d_out;

    const int knn_quads  = in_sizes[4] / 4;                 // 49152
    const int knn_blocks = (knn_quads + 255) / 256;         // 192
    const int kp_blocks  = (NB * KP + 255) / 256;           // 8

    const size_t min_bytes = (size_t)TOT_PTS * 4;           // 128 KB
    const size_t ws_need   = min_bytes + 64;
    if (ws_size >= ws_need) {
        unsigned* minarr = (unsigned*)d_ws;
        unsigned* ctrl   = (unsigned*)((char*)d_ws + min_bytes);
        float*    acc    = (float*)&ctrl[0];
        init_kernel<<<TOT_PTS / 4 / 256, 256, 0, stream>>>((uint4*)minarr, ctrl);
        main_kernel<<<GAL_BLOCKS + knn_blocks + kp_blocks, 256, 0, stream>>>(
            srcT, tgtT, minarr, skp, tkp, R, T, aknn, bknn, kptr, acc,
            knn_blocks, knn_quads);
        finalize_kernel<<<1, 1024, 0, stream>>>(minarr, acc, out);
    } else {
        zero_out_kernel<<<1, 64, 0, stream>>>(out);
        gal_direct_kernel<<<dim3(NPTS / 256, 2 * NB), 256, 0, stream>>>(srcT, tgtT, out + 1);
        kp_kernel<<<kp_blocks, 256, 0, stream>>>(skp, tkp, R, T, out);
        knn_kernel<<<knn_blocks, 256, 0, stream>>>(aknn, bknn, kptr, out, knn_quads);
    }
}